// Round 10
// baseline (163.156 us; speedup 1.0000x reference)
//
#include <hip/hip_runtime.h>
#include <math.h>

// RegimeFeatureExtractor: prices [B, T] f32 -> features [B, T, 6] f32
// R9: persistent blocks with CONTIGUOUS chunk assignment — one block per row
//     (grid = B = 1024), 8 sequential chunks per block. R8's grid-stride hop
//     was 1536*24KB = 36 MiB = 9 x 4 MiB -> every iteration aliased the same
//     L2 sets -> partial-dirty-line RMW (FETCH +206 MB, WRITE +104 MB).
//     Contiguous chunks stream: stride 24 KB, fresh sets, halo L1-resident.
//     Body identical to R7 (best validated, 51.9 µs): float2 (r,p) b64
//     staging, register-stashed slides, swizzled b128 ostage, coalesced
//     dwordx4 stores, fast rcp/sqrt/log math (absmax 128).

constexpr int BLOCK = 256;
constexpr int RPT   = 4;               // outputs per thread
constexpr int CHUNK = BLOCK * RPT;     // 1024 t per chunk
constexpr int HALO  = 21;              // need r at g=t-20 => p at g=t-21
constexpr int NS    = CHUNK + HALO;    // 1045 staged elements
#define PIDX2(e) ((e) + ((e) >> 5))    // pad 1 float2 per 32 -> conflict-free b64
constexpr int LDSF  = CHUNK * 6;       // 6144 floats = 24.6 KB (ostage = output image)
constexpr float EPS = 1e-8f;
constexpr float PI_HALF = 1.5707963267948966f;
constexpr float LN2 = 0.6931471805599453f;

typedef float f32x4 __attribute__((ext_vector_type(4)));

__device__ __forceinline__ float frcp(float x) { return __builtin_amdgcn_rcpf(x); }
__device__ __forceinline__ float fsq(float x)  { return __builtin_amdgcn_sqrtf(x); }

__global__ __launch_bounds__(BLOCK, 6)
void regime_kernel(const float* __restrict__ prices, float* __restrict__ out, int T) {
    // union: srp (float2[~1077] = 8.6 KB) during compute; ostage during store.
    __shared__ __align__(16) float lds[LDSF];
    float2* const srp  = (float2*)lds;
    f32x4*  const ost4 = (f32x4*)lds;

    const int tid = threadIdx.x;
    const int row = blockIdx.x;                    // one row per block
    const float* __restrict__ pr = prices + (size_t)row * T;

    for (int cx = 0; cx < 8; ++cx) {               // 8 contiguous chunks = one row
        const int t0 = cx * CHUNK;

        __syncthreads();   // prev iteration's ostage reads done before overwrite

        // --- stage (r, p) interleaved; r from two global loads (2nd is L1-hit) ---
        for (int i = tid; i < NS; i += BLOCK) {
            int g = t0 - HALO + i;
            float p = (g >= 0) ? pr[g] : 0.0f;
            float r = 0.0f;
            if (g >= 1) {
                float pm = pr[g - 1];
                r = (__builtin_amdgcn_logf(p + EPS) - __builtin_amdgcn_logf(pm + EPS)) * LN2;
            }
            srp[PIDX2(i)] = make_float2(r, p);
        }
        __syncthreads();

        const int tf = t0 + tid * RPT;     // first t of this thread
        const int lf = HALO + tid * RPT;   // its local index

        // ---- one pass over the 21-element window: sums + bipower + stashes ----
        float s5 = 0.f, q5 = 0.f, ps5 = 0.f;
        float s10 = 0.f, q10 = 0.f;
        float s20 = 0.f, q20 = 0.f, ps20 = 0.f;
        float A = 0.f, aprev = 0.f;
        float aA = 0.f, aB = 0.f, aprev20 = 0.f;
        float p0 = 0.f, p5v = 0.f;
        float  r10s[3];                    // r at i=9,8,7  -> r10o for k=1,2,3
        float2 s5s[3];                     // (r,p) at i=4,3,2 -> (r5o, shifted)
        float2 s20s[3];                    // (r,p) at i=19,18,17 -> (r20o, p20o)

        #pragma unroll
        for (int i = 20; i >= 0; --i) {
            float2 v = srp[PIDX2(lf - i)];
            float r = v.x, p = v.y;
            float a = fabsf(r);
            if (i == 20) { aprev20 = a; aprev = a; }
            else if (i >= 1) { A = fmaf(aprev, a, A); aprev = a; }
            if (i == 1) aA = a;                    // |r_{tf-1}|
            if (i == 0) aB = a;                    // |r_{tf}|
            if (i >= 7  && i <= 9)  r10s[9 - i]  = r;
            if (i >= 2  && i <= 4)  s5s[4 - i]   = v;
            if (i >= 17 && i <= 19) s20s[19 - i] = v;
            if (i <= 19) {
                s20 += r; q20 = fmaf(r, r, q20);
                ps20 += p;
                if (i == 5) p5v = p;
                if (i == 0) p0 = p;
                if (i <= 9) { s10 += r; q10 = fmaf(r, r, q10); }
                if (i <= 4) { s5 += r; q5 = fmaf(r, r, q5); ps5 += p; }
            }
        }

        float fb[RPT * 6];                  // constant-indexed -> VGPRs
        float pt = p0, shifted = p5v;

        #pragma unroll
        for (int k = 0; k < RPT; ++k) {
            const int t = tf + k;
            if (k > 0) {
                // slide t-1 -> t: ONE new LDS read; rest from register stashes
                float2 vn  = srp[PIDX2(lf + k)];
                float rn   = vn.x;
                float r5o  = s5s[k - 1].x;
                float r10o = r10s[k - 1];
                float2 v20 = s20s[k - 1];
                float rn2 = rn * rn;
                s5  += rn - r5o;    q5  += rn2 - r5o  * r5o;
                s10 += rn - r10o;   q10 += rn2 - r10o * r10o;
                s20 += rn - v20.x;  q20 += rn2 - v20.x * v20.x;
                pt      = vn.y;
                shifted = s5s[k - 1].y;
                ps5  += pt - shifted;
                ps20 += pt - v20.y;
                A = fmaf(aA, aB, A);                 // add pair (t-2, t-1)
                float a20n = fabsf(v20.x);
                A = fmaf(-aprev20, a20n, A);         // drop pair (t-21, t-20)
                aprev20 = a20n;
                aA = aB; aB = fabsf(rn);
            }

            float c5r, c10r, c20r, d5r, d10r, d20r;
            if (t >= 19) {
                c5r = 0.2f; c10r = 0.1f; c20r = 0.05f;
                d5r = 0.25f; d10r = 1.f / 9.f; d20r = 1.f / 19.f;
            } else {
                int tp1 = t + 1;
                float c5  = (float)(tp1 < 5  ? tp1 : 5);
                float c10 = (float)(tp1 < 10 ? tp1 : 10);
                float c20 = (float)tp1;              // t < 19 -> tp1 <= 19 < 20
                c5r  = frcp(c5);  c10r = frcp(c10);  c20r = frcp(c20);
                d5r  = frcp(fmaxf(c5  - 1.f, 1.f));
                d10r = frcp(fmaxf(c10 - 1.f, 1.f));
                d20r = frcp(fmaxf(c20 - 1.f, 1.f));
            }

            float var5  = (q5  - s5  * s5  * c5r ) * d5r;
            float var10 = (q10 - s10 * s10 * c10r) * d10r;
            float var20 = (q20 - s20 * s20 * c20r) * d20r;
            float std5  = fsq(fmaxf(var5,  0.f));
            float std10 = fsq(fmaxf(var10, 0.f));
            float std20 = fsq(fmaxf(var20, 0.f));
            const bool has2 = (t >= 1);
            float f1 = has2 ? std5  : 1e-6f;
            float f2 = has2 ? std10 : 1e-6f;
            float f3 = has2 ? std20 : 1e-6f;

            float m5  = ps5  * c5r;
            float m20 = ps20 * c20r;
            float f4 = (m5 - m20) * frcp(m20 + EPS);

            float sh = (t >= 5) ? shifted : srp[PIDX2(HALO)].y;  // chunk 0: p[0]
            float f5 = (pt - sh) * frcp(sh + EPS);

            float rvv = f3 * f3;
            float bv = (t >= 20) ? A * PI_HALF : 0.f;
            float f6 = rvv * frcp(bv + EPS);

            fb[k * 6 + 0] = f1; fb[k * 6 + 1] = f2; fb[k * 6 + 2] = f3;
            fb[k * 6 + 3] = f4; fb[k * 6 + 4] = f5; fb[k * 6 + 5] = f6;
        }

        // --- all srp reads complete; overlay ostage (swizzled output image) ---
        __syncthreads();
        #pragma unroll
        for (int m = 0; m < 6; ++m) {  // granule g = 6*tid+m, swizzled position
            int g = 6 * tid + m;
            int p = g ^ ((g >> 3) & 7);
            f32x4 v = { fb[4 * m], fb[4 * m + 1], fb[4 * m + 2], fb[4 * m + 3] };
            ost4[p] = v;
        }
        __syncthreads();

        // --- coalesced stores: 6x dwordx4 (1 KB/wave-instr), through L2 ---
        f32x4* __restrict__ outp4 = (f32x4*)(out + ((size_t)row * T + t0) * 6);
        #pragma unroll
        for (int r = 0; r < 6; ++r) {
            int g = r * BLOCK + tid;
            int p = g ^ ((g >> 3) & 7);
            outp4[g] = ost4[p];
        }
    }
}

extern "C" void kernel_launch(void* const* d_in, const int* in_sizes, int n_in,
                              void* d_out, int out_size, void* d_ws, size_t ws_size,
                              hipStream_t stream) {
    const float* prices = (const float*)d_in[0];
    float* out = (float*)d_out;
    const int T = 8192;                 // per reference setup_inputs()
    const int B = in_sizes[0] / T;      // 1024
    hipLaunchKernelGGL(regime_kernel, dim3(B), dim3(BLOCK), 0, stream,
                       prices, out, T);
}

// Round 11
// 42.308 us; speedup vs baseline: 3.8564x; 3.8564x over previous
//
#include <hip/hip_runtime.h>
#include <math.h>

// RegimeFeatureExtractor: prices [B, T] f32 -> features [B, T, 6] f32
// R10: register-resident windows. Each thread loads its 28-float price window
//      [tf-24, tf+3] as 7 coalesced f32x4 (lane-contiguous 1KB wave-reads,
//      16B-aligned, L1-absorbed 7x overlap) and computes logs/returns/window
//      sums/bipower entirely in registers — the input-side LDS (staging phase,
//      one barrier, ~250 cyc/wave of b64 reads + 4-way conflicts) is deleted.
//      LDS keeps only the validated swizzled b128 output transpose (R7).
//      Non-persistent 8192-block dispatch (persistence caused output RMW:
//      R8/R9 FETCH ~= output size). Math identical to validated R3..R7
//      (absmax 128): fast log2/rcp/sqrt, ln2 folded into the epilogue.

constexpr int BLOCK = 256;
constexpr int RPT   = 4;               // outputs per thread
constexpr int CHUNK = BLOCK * RPT;     // 1024 t per block
constexpr int LDSF  = CHUNK * 6;       // 6144 floats = 24.6 KB (output image)
constexpr float EPS = 1e-8f;
constexpr float LN2 = 0.6931471805599453f;
constexpr float PI_HALF_L2SQ = 1.5707963267948966f * LN2 * LN2;  // bv scale (log2 units)

typedef float f32x4 __attribute__((ext_vector_type(4)));

__device__ __forceinline__ float frcp(float x)  { return __builtin_amdgcn_rcpf(x); }
__device__ __forceinline__ float fsq(float x)   { return __builtin_amdgcn_sqrtf(x); }
__device__ __forceinline__ float flog2(float x) { return __builtin_amdgcn_logf(x); }

__global__ __launch_bounds__(BLOCK, 4)
void regime_kernel(const float* __restrict__ prices, float* __restrict__ out, int T) {
    __shared__ __align__(16) float lds[LDSF];
    f32x4* const ost4 = (f32x4*)lds;

    const int tid = threadIdx.x;
    const int t0  = blockIdx.x * CHUNK;
    const int row = blockIdx.y;
    const float* __restrict__ pr = prices + (size_t)row * T;

    const int tf = t0 + tid * RPT;         // first t of this thread
    const float p0row = pr[0];             // uniform; only used when t < 5

    // --- 7 coalesced f32x4 loads cover [tf-24, tf+3]; element j -> g = tf-24+j ---
    f32x4 L[7];
    if (tf >= 24) {
        const f32x4* __restrict__ src = (const f32x4*)(pr + (tf - 24));
        #pragma unroll
        for (int m = 0; m < 7; ++m) L[m] = src[m];
    } else {                                // chunk 0, tid < 6: clamped scalar fill
        #pragma unroll
        for (int m = 0; m < 7; ++m)
            #pragma unroll
            for (int e = 0; e < 4; ++e) {
                int g = tf - 24 + 4 * m + e;
                float v = pr[g > 0 ? g : 0];
                L[m][e] = (g >= 0) ? v : 0.0f;   // p = 0 for g < 0 (ref zero-pad)
            }
    }

    // ---- single register stream j=4..27 (i = 24-j = 20..-3): sums + bipower ----
    float s5 = 0.f, q5 = 0.f, ps5 = 0.f;
    float s10 = 0.f, q10 = 0.f;
    float s20 = 0.f, q20 = 0.f, ps20 = 0.f;
    float A = 0.f, aprev = 0.f;
    float aA = 0.f, aB = 0.f, aprev20 = 0.f;
    float p0 = 0.f, p5v = 0.f;
    float r10s[3], vnr[3], vnp[3];
    float2 s5s[3], s20s[3];

    float lp_prev = flog2(L[0][3] + EPS);   // j=3: g = tf-21
    #pragma unroll
    for (int j = 4; j < 28; ++j) {
        float p  = L[j >> 2][j & 3];
        float lp = flog2(p + EPS);
        float r  = lp - lp_prev;            // log2 units; ln2 folded at epilogue
        lp_prev = lp;
        if (tf < 24 && (tf - 24 + j) < 1) r = 0.0f;   // r = 0 for g < 1 (ref pad)
        float a = fabsf(r);
        const int i = 24 - j;               // distance from tf (neg = future k)
        if (i == 20) { aprev20 = a; aprev = a; }
        else if (i >= 1) { A = fmaf(aprev, a, A); aprev = a; }  // pairs to (tf-2,tf-1)
        if (i == 1) aA = a;                 // |r_{tf-1}|
        if (i == 0) aB = a;                 // |r_{tf}|
        if (i >= 7  && i <= 9)  r10s[9 - i]  = r;
        if (i >= 2  && i <= 4)  s5s[4 - i]   = make_float2(r, p);
        if (i >= 17 && i <= 19) s20s[19 - i] = make_float2(r, p);
        if (i <= -1) { vnr[-i - 1] = r; vnp[-i - 1] = p; }      // slide feed k=1..3
        if (i >= 0 && i <= 19) {
            s20 += r; q20 = fmaf(r, r, q20); ps20 += p;
            if (i == 5) p5v = p;
            if (i == 0) p0 = p;
            if (i <= 9) { s10 += r; q10 = fmaf(r, r, q10); }
            if (i <= 4) { s5 += r; q5 = fmaf(r, r, q5); ps5 += p; }
        }
    }

    float fb[RPT * 6];                      // constant-indexed -> VGPRs
    float pt = p0, shifted = p5v;

    #pragma unroll
    for (int k = 0; k < RPT; ++k) {
        const int t = tf + k;
        if (k > 0) {
            // slide t-1 -> t, fully from registers
            float rn   = vnr[k - 1];
            float r5o  = s5s[k - 1].x;
            float r10o = r10s[k - 1];
            float2 v20 = s20s[k - 1];
            float rn2 = rn * rn;
            s5  += rn - r5o;    q5  += rn2 - r5o  * r5o;
            s10 += rn - r10o;   q10 += rn2 - r10o * r10o;
            s20 += rn - v20.x;  q20 += rn2 - v20.x * v20.x;
            pt      = vnp[k - 1];
            shifted = s5s[k - 1].y;
            ps5  += pt - shifted;
            ps20 += pt - v20.y;
            A = fmaf(aA, aB, A);                 // add pair (t-2, t-1)
            float a20n = fabsf(v20.x);
            A = fmaf(-aprev20, a20n, A);         // drop pair (t-21, t-20)
            aprev20 = a20n;
            aA = aB; aB = fabsf(rn);
        }

        float c5r, c10r, c20r, d5r, d10r, d20r;
        if (t >= 19) {
            c5r = 0.2f; c10r = 0.1f; c20r = 0.05f;
            d5r = 0.25f; d10r = 1.f / 9.f; d20r = 1.f / 19.f;
        } else {
            int tp1 = t + 1;
            float c5  = (float)(tp1 < 5  ? tp1 : 5);
            float c10 = (float)(tp1 < 10 ? tp1 : 10);
            float c20 = (float)tp1;              // t < 19 -> tp1 <= 19 < 20
            c5r  = frcp(c5);  c10r = frcp(c10);  c20r = frcp(c20);
            d5r  = frcp(fmaxf(c5  - 1.f, 1.f));
            d10r = frcp(fmaxf(c10 - 1.f, 1.f));
            d20r = frcp(fmaxf(c20 - 1.f, 1.f));
        }

        // vars in log2 units; multiply std by ln2 to recover ln-scaled features
        float var5  = (q5  - s5  * s5  * c5r ) * d5r;
        float var10 = (q10 - s10 * s10 * c10r) * d10r;
        float var20 = (q20 - s20 * s20 * c20r) * d20r;
        float std5  = fsq(fmaxf(var5,  0.f)) * LN2;
        float std10 = fsq(fmaxf(var10, 0.f)) * LN2;
        float std20 = fsq(fmaxf(var20, 0.f)) * LN2;
        const bool has2 = (t >= 1);
        float f1 = has2 ? std5  : 1e-6f;
        float f2 = has2 ? std10 : 1e-6f;
        float f3 = has2 ? std20 : 1e-6f;

        float m5  = ps5  * c5r;
        float m20 = ps20 * c20r;
        float f4 = (m5 - m20) * frcp(m20 + EPS);

        float sh = (t >= 5) ? shifted : p0row;
        float f5 = (pt - sh) * frcp(sh + EPS);

        float rvv = f3 * f3;                       // ln-scaled rv
        float bv = (t >= 20) ? A * PI_HALF_L2SQ : 0.f;  // ln2^2-scaled bipower
        float f6 = rvv * frcp(bv + EPS);

        fb[k * 6 + 0] = f1; fb[k * 6 + 1] = f2; fb[k * 6 + 2] = f3;
        fb[k * 6 + 3] = f4; fb[k * 6 + 4] = f5; fb[k * 6 + 5] = f6;
    }

    // --- swizzled output image in LDS (validated R7 transpose) ---
    #pragma unroll
    for (int m = 0; m < 6; ++m) {          // granule g = 6*tid+m, swizzled slot
        int g = 6 * tid + m;
        int p = g ^ ((g >> 3) & 7);
        f32x4 v = { fb[4 * m], fb[4 * m + 1], fb[4 * m + 2], fb[4 * m + 3] };
        ost4[p] = v;
    }
    __syncthreads();

    // --- coalesced stores: 6x dwordx4 (1 KB/wave-instr), through L2 ---
    f32x4* __restrict__ outp4 = (f32x4*)(out + ((size_t)row * T + t0) * 6);
    #pragma unroll
    for (int r = 0; r < 6; ++r) {
        int g = r * BLOCK + tid;
        int p = g ^ ((g >> 3) & 7);
        outp4[g] = ost4[p];
    }
}

extern "C" void kernel_launch(void* const* d_in, const int* in_sizes, int n_in,
                              void* d_out, int out_size, void* d_ws, size_t ws_size,
                              hipStream_t stream) {
    const float* prices = (const float*)d_in[0];
    float* out = (float*)d_out;
    const int T = 8192;                 // per reference setup_inputs()
    const int B = in_sizes[0] / T;      // 1024
    dim3 grid(T / CHUNK, B);
    hipLaunchKernelGGL(regime_kernel, grid, dim3(BLOCK), 0, stream, prices, out, T);
}